// Round 1
// baseline (608.367 us; speedup 1.0000x reference)
//
#include <hip/hip_runtime.h>
#include <math.h>

#define N_NODES 20000
#define N_EDGES 320000
#define EP (N_EDGES + N_NODES)   // with self loops
#define HEADS 5

// ---------------- CSR build ----------------
__global__ void count_deg_k(const int* __restrict__ ei, int* __restrict__ deg) {
  int e = blockIdx.x * blockDim.x + threadIdx.x;
  if (e >= EP) return;
  int dst = (e < N_EDGES) ? ei[N_EDGES + e] : (e - N_EDGES);
  atomicAdd(&deg[dst], 1);
}

__global__ __launch_bounds__(1024) void scan_k(const int* __restrict__ deg,
                                               int* __restrict__ offs) {
  __shared__ int buf[1024];
  __shared__ int carry;
  int tid = threadIdx.x;
  if (tid == 0) carry = 0;
  __syncthreads();
  for (int base = 0; base < N_NODES; base += 1024) {
    int i = base + tid;
    int v = (i < N_NODES) ? deg[i] : 0;
    buf[tid] = v;
    __syncthreads();
    for (int o = 1; o < 1024; o <<= 1) {
      int t = (tid >= o) ? buf[tid - o] : 0;
      __syncthreads();
      buf[tid] += t;
      __syncthreads();
    }
    int excl = carry + buf[tid] - v;   // exclusive prefix
    int tot = buf[1023];
    __syncthreads();
    if (i < N_NODES) offs[i] = excl;
    if (tid == 0) carry += tot;
    __syncthreads();
  }
  if (tid == 0) offs[N_NODES] = carry;
}

__global__ void scatter_k(const int* __restrict__ ei, const int* __restrict__ offs,
                          int* __restrict__ cursor, int* __restrict__ ssrc) {
  int e = blockIdx.x * blockDim.x + threadIdx.x;
  if (e >= EP) return;
  int src, dst;
  if (e < N_EDGES) { src = ei[e]; dst = ei[N_EDGES + e]; }
  else             { src = e - N_EDGES; dst = src; }
  int pos = atomicAdd(&cursor[dst], 1);
  ssrc[offs[dst] + pos] = src;
}

// ---------------- fp32 tiled GEMM: C[M,N] = A[M,K] @ B[K,N] ----------------
// BM=BN=64, BK=16, 256 threads, 4x4 per thread. K must be a multiple of 16.
__global__ __launch_bounds__(256) void sgemm_k(const float* __restrict__ A,
                                               const float* __restrict__ B,
                                               float* __restrict__ C,
                                               int M, int N, int K) {
  __shared__ float As[16][65];  // [k][m], +1 pad
  __shared__ float Bs[16][65];  // [k][n], +1 pad
  int bm = blockIdx.x * 64, bn = blockIdx.y * 64;
  int tid = threadIdx.x;
  int tr = (tid / 16) * 4;   // row offset in C tile
  int tc = (tid % 16) * 4;   // col offset in C tile
  float acc[4][4] = {};

  int arow = tid >> 2, ac4 = (tid & 3) << 2;     // A: 64 rows x 16 cols
  int brow = tid >> 4, bc4 = (tid & 15) << 2;    // B: 16 rows x 64 cols

  for (int k0 = 0; k0 < K; k0 += 16) {
    float4 a;
    if (bm + arow < M) a = *(const float4*)&A[(size_t)(bm + arow) * K + k0 + ac4];
    else               a = make_float4(0.f, 0.f, 0.f, 0.f);
    As[ac4 + 0][arow] = a.x; As[ac4 + 1][arow] = a.y;
    As[ac4 + 2][arow] = a.z; As[ac4 + 3][arow] = a.w;

    float4 b;
    if (bn + bc4 < N) b = *(const float4*)&B[(size_t)(k0 + brow) * N + bn + bc4];
    else              b = make_float4(0.f, 0.f, 0.f, 0.f);
    Bs[brow][bc4 + 0] = b.x; Bs[brow][bc4 + 1] = b.y;
    Bs[brow][bc4 + 2] = b.z; Bs[brow][bc4 + 3] = b.w;
    __syncthreads();

#pragma unroll
    for (int k = 0; k < 16; k++) {
      float av[4], bv[4];
#pragma unroll
      for (int j = 0; j < 4; j++) { av[j] = As[k][tr + j]; bv[j] = Bs[k][tc + j]; }
#pragma unroll
      for (int i = 0; i < 4; i++)
#pragma unroll
        for (int j = 0; j < 4; j++) acc[i][j] += av[i] * bv[j];
    }
    __syncthreads();
  }

#pragma unroll
  for (int i = 0; i < 4; i++) {
    int r = bm + tr + i;
    if (r >= M) break;
#pragma unroll
    for (int j = 0; j < 4; j++) {
      int c = bn + tc + j;
      if (c < N) C[(size_t)r * N + c] = acc[i][j];
    }
  }
}

// ---------------- per-(node,head) attention sums ----------------
// one wave per (n,h); 4 waves per block of 256
template <int C>
__global__ __launch_bounds__(256) void att_sums_k(const float* __restrict__ xw,
                                                  const float* __restrict__ att_s,
                                                  const float* __restrict__ att_d,
                                                  float* __restrict__ a_s,
                                                  float* __restrict__ a_d) {
  int wid = blockIdx.x * (blockDim.x >> 6) + (threadIdx.x >> 6);
  int lane = threadIdx.x & 63;
  if (wid >= N_NODES * HEADS) return;
  int n = wid / HEADS, h = wid % HEADS;
  float ss = 0.f, sd = 0.f;
  if (lane < C) {
    float v = xw[(size_t)n * (HEADS * C) + h * C + lane];
    ss = v * att_s[h * C + lane];
    sd = v * att_d[h * C + lane];
  }
#pragma unroll
  for (int o = C / 2; o > 0; o >>= 1) {
    ss += __shfl_down(ss, o);
    sd += __shfl_down(sd, o);
  }
  if (lane == 0) { a_s[wid] = ss; a_d[wid] = sd; }
}

// ---------------- per-(node,head) scatter-softmax -> alpha per edge ----------------
__global__ void softmax_alpha_k(const int* __restrict__ offs, const int* __restrict__ ssrc,
                                const float* __restrict__ a_s, const float* __restrict__ a_d,
                                float* __restrict__ alpha) {
  int t = blockIdx.x * blockDim.x + threadIdx.x;   // (n,h) pair
  if (t >= N_NODES * HEADS) return;
  int n = t / HEADS, h = t % HEADS;
  int off = offs[n], end = offs[n + 1];
  float ad = a_d[t];
  float m = -1e30f;
  for (int i = off; i < end; ++i) {
    float s = a_s[ssrc[i] * HEADS + h] + ad;
    s = (s > 0.f) ? s : 0.2f * s;        // leaky_relu, slope 0.2
    alpha[(size_t)i * HEADS + h] = s;
    m = fmaxf(m, s);
  }
  float den = 0.f;
  for (int i = off; i < end; ++i) {
    float p = expf(alpha[(size_t)i * HEADS + h] - m);
    alpha[(size_t)i * HEADS + h] = p;
    den += p;
  }
  float inv = 1.f / (den + 1e-16f);
  for (int i = off; i < end; ++i) alpha[(size_t)i * HEADS + h] *= inv;
}

// ---------------- aggregation: out[n,c] = act(mean_h sum_e alpha*xw[src] + b) ----------------
// block = 320 threads = 5 waves (one per head); lane -> channel (C=64) or
// 2 edge-groups x 32 channels (C=32)
template <int C>
__global__ __launch_bounds__(320) void gat_aggregate_k(const int* __restrict__ offs,
                                                       const int* __restrict__ ssrc,
                                                       const float* __restrict__ alpha,
                                                       const float* __restrict__ xw,
                                                       const float* __restrict__ bias,
                                                       float* __restrict__ out0,
                                                       float* __restrict__ out1,
                                                       int act_relu) {
  constexpr int GP = 64 / C;   // edges in flight per wave
  int n = blockIdx.x;
  int wave = threadIdx.x >> 6;       // head
  int lane = threadIdx.x & 63;
  int grp = lane / C, c = lane % C;
  int off = offs[n], end = offs[n + 1];
  float acc = 0.f;
  for (int i = off + grp; i < end; i += GP) {
    int s = ssrc[i];
    acc += alpha[(size_t)i * HEADS + wave] * xw[(size_t)s * (HEADS * C) + wave * C + c];
  }
  if constexpr (GP == 2) acc += __shfl_xor(acc, 32);
  __shared__ float sacc[HEADS][C];
  if (grp == 0) sacc[wave][c] = acc;
  __syncthreads();
  if (threadIdx.x < C) {
    float v = 0.f;
#pragma unroll
    for (int h = 0; h < HEADS; h++) v += sacc[h][threadIdx.x];
    v = v * (1.f / HEADS) + bias[threadIdx.x];
    if (act_relu) v = fmaxf(v, 0.f);
    out0[(size_t)n * C + threadIdx.x] = v;
    if (out1) out1[(size_t)n * C + threadIdx.x] = v;
  }
}

// ---------------- launch ----------------
extern "C" void kernel_launch(void* const* d_in, const int* in_sizes, int n_in,
                              void* d_out, int out_size, void* d_ws, size_t ws_size,
                              hipStream_t stream) {
  const float* x        = (const float*)d_in[0];
  const int*   ei       = (const int*)d_in[1];
  const float* W1       = (const float*)d_in[2];
  const float* att_src1 = (const float*)d_in[3];
  const float* att_dst1 = (const float*)d_in[4];
  const float* b1       = (const float*)d_in[5];
  const float* W2       = (const float*)d_in[6];
  const float* att_src2 = (const float*)d_in[7];
  const float* att_dst2 = (const float*)d_in[8];
  const float* b2       = (const float*)d_in[9];
  const float* W3       = (const float*)d_in[10];
  const float* att_src3 = (const float*)d_in[11];
  const float* att_dst3 = (const float*)d_in[12];
  const float* b3       = (const float*)d_in[13];
  float* out = (float*)d_out;

  char* w = (char*)d_ws;
  auto alloc = [&](size_t bytes) -> void* {
    void* p = (void*)w;
    w += (bytes + 255) & ~(size_t)255;
    return p;
  };
  int*   deg    = (int*)alloc((size_t)N_NODES * 4);
  int*   offs   = (int*)alloc((size_t)(N_NODES + 1) * 4);
  int*   cursor = (int*)alloc((size_t)N_NODES * 4);
  int*   ssrc   = (int*)alloc((size_t)EP * 4);
  float* xw     = (float*)alloc((size_t)N_NODES * 320 * 4);   // reused by all layers
  float* a_s    = (float*)alloc((size_t)N_NODES * HEADS * 4);
  float* a_d    = (float*)alloc((size_t)N_NODES * HEADS * 4);
  float* alpha  = (float*)alloc((size_t)EP * HEADS * 4);      // reused by all layers
  float* h1     = (float*)alloc((size_t)N_NODES * 64 * 4);

  hipMemsetAsync(deg, 0, (size_t)N_NODES * 4, stream);
  hipMemsetAsync(cursor, 0, (size_t)N_NODES * 4, stream);

  int eb = (EP + 255) / 256;
  count_deg_k<<<eb, 256, 0, stream>>>(ei, deg);
  scan_k<<<1, 1024, 0, stream>>>(deg, offs);
  scatter_k<<<eb, 256, 0, stream>>>(ei, offs, cursor, ssrc);

  int nh_waves_blocks = (N_NODES * HEADS + 3) / 4;        // 4 waves/block
  int nh_thread_blocks = (N_NODES * HEADS + 255) / 256;

  // ---- layer 1: GAT(x; W1) -> h1 [N,64], relu ----
  {
    dim3 g((N_NODES + 63) / 64, (320 + 63) / 64);
    sgemm_k<<<g, 256, 0, stream>>>(x, W1, xw, N_NODES, 320, 256);
    att_sums_k<64><<<nh_waves_blocks, 256, 0, stream>>>(xw, att_src1, att_dst1, a_s, a_d);
    softmax_alpha_k<<<nh_thread_blocks, 256, 0, stream>>>(offs, ssrc, a_s, a_d, alpha);
    gat_aggregate_k<64><<<N_NODES, 320, 0, stream>>>(offs, ssrc, alpha, xw, b1,
                                                     h1, nullptr, 1);
  }
  // ---- layer 2: GAT(h1; W2) -> mu [N,32], identity; write to out slot0 (z) and slot1 (mu) ----
  {
    dim3 g((N_NODES + 63) / 64, (160 + 63) / 64);
    sgemm_k<<<g, 256, 0, stream>>>(h1, W2, xw, N_NODES, 160, 64);
    att_sums_k<32><<<nh_waves_blocks, 256, 0, stream>>>(xw, att_src2, att_dst2, a_s, a_d);
    softmax_alpha_k<<<nh_thread_blocks, 256, 0, stream>>>(offs, ssrc, a_s, a_d, alpha);
    gat_aggregate_k<32><<<N_NODES, 320, 0, stream>>>(offs, ssrc, alpha, xw, b2,
                                                     out, out + (size_t)N_NODES * 32, 0);
  }
  // ---- layer 3: GAT(h1; W3) -> logvar [N,32], identity; write to out slot2 ----
  {
    dim3 g((N_NODES + 63) / 64, (160 + 63) / 64);
    sgemm_k<<<g, 256, 0, stream>>>(h1, W3, xw, N_NODES, 160, 64);
    att_sums_k<32><<<nh_waves_blocks, 256, 0, stream>>>(xw, att_src3, att_dst3, a_s, a_d);
    softmax_alpha_k<<<nh_thread_blocks, 256, 0, stream>>>(offs, ssrc, a_s, a_d, alpha);
    gat_aggregate_k<32><<<N_NODES, 320, 0, stream>>>(offs, ssrc, alpha, xw, b3,
                                                     out + (size_t)2 * N_NODES * 32, nullptr, 0);
  }
}

// Round 2
// 413.742 us; speedup vs baseline: 1.4704x; 1.4704x over previous
//
#include <hip/hip_runtime.h>
#include <math.h>

#define N_NODES 20000
#define N_EDGES 320000
#define EP (N_EDGES + N_NODES)   // with self loops
#define HEADS 5

// ---------------- CSR build ----------------
__global__ void count_deg_k(const int* __restrict__ ei, int* __restrict__ deg) {
  int e = blockIdx.x * blockDim.x + threadIdx.x;
  if (e >= EP) return;
  int dst = (e < N_EDGES) ? ei[N_EDGES + e] : (e - N_EDGES);
  atomicAdd(&deg[dst], 1);
}

__global__ __launch_bounds__(1024) void scan_k(const int* __restrict__ deg,
                                               int* __restrict__ offs) {
  __shared__ int buf[1024];
  __shared__ int carry;
  int tid = threadIdx.x;
  if (tid == 0) carry = 0;
  __syncthreads();
  for (int base = 0; base < N_NODES; base += 1024) {
    int i = base + tid;
    int v = (i < N_NODES) ? deg[i] : 0;
    buf[tid] = v;
    __syncthreads();
    for (int o = 1; o < 1024; o <<= 1) {
      int t = (tid >= o) ? buf[tid - o] : 0;
      __syncthreads();
      buf[tid] += t;
      __syncthreads();
    }
    int excl = carry + buf[tid] - v;   // exclusive prefix
    int tot = buf[1023];
    __syncthreads();
    if (i < N_NODES) offs[i] = excl;
    if (tid == 0) carry += tot;
    __syncthreads();
  }
  if (tid == 0) offs[N_NODES] = carry;
}

__global__ void scatter_k(const int* __restrict__ ei, const int* __restrict__ offs,
                          int* __restrict__ cursor, int* __restrict__ ssrc) {
  int e = blockIdx.x * blockDim.x + threadIdx.x;
  if (e >= EP) return;
  int src, dst;
  if (e < N_EDGES) { src = ei[e]; dst = ei[N_EDGES + e]; }
  else             { src = e - N_EDGES; dst = src; }
  int pos = atomicAdd(&cursor[dst], 1);
  ssrc[offs[dst] + pos] = src;
}

// ---------------- pack [W2 | W3] into Wc[64][320] ----------------
__global__ void pack23_k(const float* __restrict__ W2, const float* __restrict__ W3,
                         float* __restrict__ Wc) {
  int t = blockIdx.x * blockDim.x + threadIdx.x;   // 64*160
  if (t >= 64 * 160) return;
  int k = t / 160, j = t % 160;
  Wc[k * 320 + j]       = W2[t];
  Wc[k * 320 + 160 + j] = W3[t];
}

// ---------------- fp32 tiled GEMM: C[M,N] = A[M,K] @ B[K,N] ----------------
// BM=BN=64, BK=16, 256 threads, 4x4 per thread. K multiple of 16.
__global__ __launch_bounds__(256) void sgemm_k(const float* __restrict__ A,
                                               const float* __restrict__ B,
                                               float* __restrict__ C,
                                               int M, int N, int K) {
  __shared__ float As[16][65];
  __shared__ float Bs[16][65];
  int bm = blockIdx.x * 64, bn = blockIdx.y * 64;
  int tid = threadIdx.x;
  int tr = (tid / 16) * 4;
  int tc = (tid % 16) * 4;
  float acc[4][4] = {};

  int arow = tid >> 2, ac4 = (tid & 3) << 2;
  int brow = tid >> 4, bc4 = (tid & 15) << 2;

  for (int k0 = 0; k0 < K; k0 += 16) {
    float4 a;
    if (bm + arow < M) a = *(const float4*)&A[(size_t)(bm + arow) * K + k0 + ac4];
    else               a = make_float4(0.f, 0.f, 0.f, 0.f);
    As[ac4 + 0][arow] = a.x; As[ac4 + 1][arow] = a.y;
    As[ac4 + 2][arow] = a.z; As[ac4 + 3][arow] = a.w;

    float4 b;
    if (bn + bc4 < N) b = *(const float4*)&B[(size_t)(k0 + brow) * N + bn + bc4];
    else              b = make_float4(0.f, 0.f, 0.f, 0.f);
    Bs[brow][bc4 + 0] = b.x; Bs[brow][bc4 + 1] = b.y;
    Bs[brow][bc4 + 2] = b.z; Bs[brow][bc4 + 3] = b.w;
    __syncthreads();

#pragma unroll
    for (int k = 0; k < 16; k++) {
      float av[4], bv[4];
#pragma unroll
      for (int j = 0; j < 4; j++) { av[j] = As[k][tr + j]; bv[j] = Bs[k][tc + j]; }
#pragma unroll
      for (int i = 0; i < 4; i++)
#pragma unroll
        for (int j = 0; j < 4; j++) acc[i][j] += av[i] * bv[j];
    }
    __syncthreads();
  }

#pragma unroll
  for (int i = 0; i < 4; i++) {
    int r = bm + tr + i;
    if (r >= M) break;
#pragma unroll
    for (int j = 0; j < 4; j++) {
      int c = bn + tc + j;
      if (c < N) C[(size_t)r * N + c] = acc[i][j];
    }
  }
}

// ---------------- per-(node,head) attention sums ----------------
// one wave per (n,h); generic row stride + column base
template <int C>
__global__ __launch_bounds__(256) void att_sums_k(const float* __restrict__ xw,
                                                  int stride,
                                                  const float* __restrict__ att_s,
                                                  const float* __restrict__ att_d,
                                                  float* __restrict__ a_s,
                                                  float* __restrict__ a_d) {
  int wid = blockIdx.x * (blockDim.x >> 6) + (threadIdx.x >> 6);
  int lane = threadIdx.x & 63;
  if (wid >= N_NODES * HEADS) return;
  int n = wid / HEADS, h = wid % HEADS;
  float ss = 0.f, sd = 0.f;
  if (lane < C) {
    float v = xw[(size_t)n * stride + h * C + lane];
    ss = v * att_s[h * C + lane];
    sd = v * att_d[h * C + lane];
  }
#pragma unroll
  for (int o = C / 2; o > 0; o >>= 1) {
    ss += __shfl_down(ss, o);
    sd += __shfl_down(sd, o);
  }
  if (lane == 0) { a_s[wid] = ss; a_d[wid] = sd; }
}

__device__ __forceinline__ float lrelu(float s) { return (s > 0.f) ? s : 0.2f * s; }

// ---------------- layer-1 fused softmax + aggregate (C=64, relu) ----------------
// block = 320 = 5 waves (wave = head); xw rows are 320 floats (=80 float4)
__global__ __launch_bounds__(320) void agg1_k(const int* __restrict__ offs,
                                              const int* __restrict__ ssrc,
                                              const float* __restrict__ a_s,
                                              const float* __restrict__ a_d,
                                              const float4* __restrict__ xw4,
                                              const float* __restrict__ bias,
                                              float* __restrict__ out) {
  int n = blockIdx.x;
  int h = threadIdx.x >> 6;
  int lane = threadIdx.x & 63;
  int off = offs[n], end = offs[n + 1];
  float ad = a_d[n * HEADS + h];

  // phase 1a: segment max (lane = edge)
  float m = -1e30f;
  for (int i = off + lane; i < end; i += 64)
    m = fmaxf(m, lrelu(a_s[ssrc[i] * HEADS + h] + ad));
#pragma unroll
  for (int o = 32; o > 0; o >>= 1) m = fmaxf(m, __shfl_xor(m, o));

  // phase 1b: denom
  float den = 0.f;
  for (int i = off + lane; i < end; i += 64)
    den += __expf(lrelu(a_s[ssrc[i] * HEADS + h] + ad) - m);
#pragma unroll
  for (int o = 32; o > 0; o >>= 1) den += __shfl_xor(den, o);
  float inv = 1.f / (den + 1e-16f);

  // phase 2: weighted gather, 4 edges in flight (16 lanes x float4 per row)
  int g = lane >> 4, q = lane & 15;
  float4 acc = make_float4(0.f, 0.f, 0.f, 0.f);
  for (int base = off; base < end; base += 4) {
    int e = base + g;
    if (e < end) {
      int s = ssrc[e];
      float alpha = __expf(lrelu(a_s[s * HEADS + h] + ad) - m) * inv;
      float4 v = xw4[(size_t)s * 80 + h * 16 + q];
      acc.x += alpha * v.x; acc.y += alpha * v.y;
      acc.z += alpha * v.z; acc.w += alpha * v.w;
    }
  }
#pragma unroll
  for (int o = 16; o <= 32; o <<= 1) {
    acc.x += __shfl_xor(acc.x, o); acc.y += __shfl_xor(acc.y, o);
    acc.z += __shfl_xor(acc.z, o); acc.w += __shfl_xor(acc.w, o);
  }

  __shared__ float sacc[HEADS][64];
  if (lane < 16) *(float4*)&sacc[h][lane * 4] = acc;
  __syncthreads();
  if (threadIdx.x < 64) {
    float v = 0.f;
#pragma unroll
    for (int hh = 0; hh < HEADS; hh++) v += sacc[hh][threadIdx.x];
    v = v * (1.f / HEADS) + bias[threadIdx.x];
    out[(size_t)n * 64 + threadIdx.x] = fmaxf(v, 0.f);
  }
}

// ---------------- layers 2+3 fused softmax + aggregate (C=32 each) ----------------
// xw rows are 320 floats: cols [0,160) = layer2 (5 heads x 32), [160,320) = layer3
__global__ __launch_bounds__(320) void agg23_k(const int* __restrict__ offs,
                                               const int* __restrict__ ssrc,
                                               const float* __restrict__ a_s2,
                                               const float* __restrict__ a_d2,
                                               const float* __restrict__ a_s3,
                                               const float* __restrict__ a_d3,
                                               const float4* __restrict__ xw4,
                                               const float* __restrict__ b2,
                                               const float* __restrict__ b3,
                                               float* __restrict__ z_out,
                                               float* __restrict__ mu_out,
                                               float* __restrict__ lv_out) {
  int n = blockIdx.x;
  int h = threadIdx.x >> 6;
  int lane = threadIdx.x & 63;
  int off = offs[n], end = offs[n + 1];
  float ad2 = a_d2[n * HEADS + h], ad3 = a_d3[n * HEADS + h];

  float m2 = -1e30f, m3 = -1e30f;
  for (int i = off + lane; i < end; i += 64) {
    int s = ssrc[i];
    m2 = fmaxf(m2, lrelu(a_s2[s * HEADS + h] + ad2));
    m3 = fmaxf(m3, lrelu(a_s3[s * HEADS + h] + ad3));
  }
#pragma unroll
  for (int o = 32; o > 0; o >>= 1) {
    m2 = fmaxf(m2, __shfl_xor(m2, o));
    m3 = fmaxf(m3, __shfl_xor(m3, o));
  }
  float den2 = 0.f, den3 = 0.f;
  for (int i = off + lane; i < end; i += 64) {
    int s = ssrc[i];
    den2 += __expf(lrelu(a_s2[s * HEADS + h] + ad2) - m2);
    den3 += __expf(lrelu(a_s3[s * HEADS + h] + ad3) - m3);
  }
#pragma unroll
  for (int o = 32; o > 0; o >>= 1) {
    den2 += __shfl_xor(den2, o);
    den3 += __shfl_xor(den3, o);
  }
  float inv2 = 1.f / (den2 + 1e-16f), inv3 = 1.f / (den3 + 1e-16f);

  // phase 2: 8 edges in flight (8 lanes x float4 per 32-float row), both layers
  int g = lane >> 3, q = lane & 7;
  float4 acc2 = make_float4(0.f, 0.f, 0.f, 0.f);
  float4 acc3 = make_float4(0.f, 0.f, 0.f, 0.f);
  for (int base = off; base < end; base += 8) {
    int e = base + g;
    if (e < end) {
      int s = ssrc[e];
      float al2 = __expf(lrelu(a_s2[s * HEADS + h] + ad2) - m2) * inv2;
      float al3 = __expf(lrelu(a_s3[s * HEADS + h] + ad3) - m3) * inv3;
      float4 v2 = xw4[(size_t)s * 80 + h * 8 + q];
      float4 v3 = xw4[(size_t)s * 80 + 40 + h * 8 + q];
      acc2.x += al2 * v2.x; acc2.y += al2 * v2.y;
      acc2.z += al2 * v2.z; acc2.w += al2 * v2.w;
      acc3.x += al3 * v3.x; acc3.y += al3 * v3.y;
      acc3.z += al3 * v3.z; acc3.w += al3 * v3.w;
    }
  }
#pragma unroll
  for (int o = 8; o <= 32; o <<= 1) {
    acc2.x += __shfl_xor(acc2.x, o); acc2.y += __shfl_xor(acc2.y, o);
    acc2.z += __shfl_xor(acc2.z, o); acc2.w += __shfl_xor(acc2.w, o);
    acc3.x += __shfl_xor(acc3.x, o); acc3.y += __shfl_xor(acc3.y, o);
    acc3.z += __shfl_xor(acc3.z, o); acc3.w += __shfl_xor(acc3.w, o);
  }

  __shared__ float s2[HEADS][32], s3[HEADS][32];
  if (lane < 8) {
    *(float4*)&s2[h][lane * 4] = acc2;
    *(float4*)&s3[h][lane * 4] = acc3;
  }
  __syncthreads();
  if (threadIdx.x < 32) {
    int t = threadIdx.x;
    float v = 0.f;
#pragma unroll
    for (int hh = 0; hh < HEADS; hh++) v += s2[hh][t];
    v = v * (1.f / HEADS) + b2[t];
    z_out[(size_t)n * 32 + t] = v;
    mu_out[(size_t)n * 32 + t] = v;
  } else if (threadIdx.x < 64) {
    int t = threadIdx.x - 32;
    float v = 0.f;
#pragma unroll
    for (int hh = 0; hh < HEADS; hh++) v += s3[hh][t];
    v = v * (1.f / HEADS) + b3[t];
    lv_out[(size_t)n * 32 + t] = v;
  }
}

// ---------------- launch ----------------
extern "C" void kernel_launch(void* const* d_in, const int* in_sizes, int n_in,
                              void* d_out, int out_size, void* d_ws, size_t ws_size,
                              hipStream_t stream) {
  const float* x        = (const float*)d_in[0];
  const int*   ei       = (const int*)d_in[1];
  const float* W1       = (const float*)d_in[2];
  const float* att_src1 = (const float*)d_in[3];
  const float* att_dst1 = (const float*)d_in[4];
  const float* b1       = (const float*)d_in[5];
  const float* W2       = (const float*)d_in[6];
  const float* att_src2 = (const float*)d_in[7];
  const float* att_dst2 = (const float*)d_in[8];
  const float* b2       = (const float*)d_in[9];
  const float* W3       = (const float*)d_in[10];
  const float* att_src3 = (const float*)d_in[11];
  const float* att_dst3 = (const float*)d_in[12];
  const float* b3       = (const float*)d_in[13];
  float* out = (float*)d_out;

  char* w = (char*)d_ws;
  auto alloc = [&](size_t bytes) -> void* {
    void* p = (void*)w;
    w += (bytes + 255) & ~(size_t)255;
    return p;
  };
  int*   deg    = (int*)alloc((size_t)N_NODES * 4);
  int*   offs   = (int*)alloc((size_t)(N_NODES + 1) * 4);
  int*   cursor = (int*)alloc((size_t)N_NODES * 4);
  int*   ssrc   = (int*)alloc((size_t)EP * 4);
  float* xw     = (float*)alloc((size_t)N_NODES * 320 * 4);   // xw1, then xwc(2|3)
  float* a_s2   = (float*)alloc((size_t)N_NODES * HEADS * 4);
  float* a_d2   = (float*)alloc((size_t)N_NODES * HEADS * 4);
  float* a_s3   = (float*)alloc((size_t)N_NODES * HEADS * 4);
  float* a_d3   = (float*)alloc((size_t)N_NODES * HEADS * 4);
  float* h1     = (float*)alloc((size_t)N_NODES * 64 * 4);
  float* Wc     = (float*)alloc((size_t)64 * 320 * 4);

  hipMemsetAsync(deg, 0, (size_t)N_NODES * 4, stream);
  hipMemsetAsync(cursor, 0, (size_t)N_NODES * 4, stream);

  int eb = (EP + 255) / 256;
  count_deg_k<<<eb, 256, 0, stream>>>(ei, deg);
  scan_k<<<1, 1024, 0, stream>>>(deg, offs);
  scatter_k<<<eb, 256, 0, stream>>>(ei, offs, cursor, ssrc);
  pack23_k<<<40, 256, 0, stream>>>(W2, W3, Wc);

  int nh_waves_blocks = (N_NODES * HEADS + 3) / 4;   // 4 waves/block of 256

  // ---- layer 1: GAT(x; W1) -> h1 [N,64], relu ----
  {
    dim3 g((N_NODES + 63) / 64, 5);
    sgemm_k<<<g, 256, 0, stream>>>(x, W1, xw, N_NODES, 320, 256);
    att_sums_k<64><<<nh_waves_blocks, 256, 0, stream>>>(xw, 320, att_src1, att_dst1, a_s2, a_d2);
    agg1_k<<<N_NODES, 320, 0, stream>>>(offs, ssrc, a_s2, a_d2, (const float4*)xw, b1, h1);
  }
  // ---- layers 2+3 fused: GAT(h1; [W2|W3]) -> mu/logvar [N,32] each ----
  {
    dim3 g((N_NODES + 63) / 64, 5);
    sgemm_k<<<g, 256, 0, stream>>>(h1, Wc, xw, N_NODES, 320, 64);
    att_sums_k<32><<<nh_waves_blocks, 256, 0, stream>>>(xw, 320, att_src2, att_dst2, a_s2, a_d2);
    att_sums_k<32><<<nh_waves_blocks, 256, 0, stream>>>(xw + 160, 320, att_src3, att_dst3, a_s3, a_d3);
    agg23_k<<<N_NODES, 320, 0, stream>>>(offs, ssrc, a_s2, a_d2, a_s3, a_d3,
                                         (const float4*)xw, b2, b3,
                                         out, out + (size_t)N_NODES * 32,
                                         out + (size_t)2 * N_NODES * 32);
  }
}

// Round 6
// 361.928 us; speedup vs baseline: 1.6809x; 1.1432x over previous
//
#include <hip/hip_runtime.h>
#include <math.h>

#define N_NODES 20000
#define N_EDGES 320000
#define EP (N_EDGES + N_NODES)   // with self loops
#define HEADS 5

__device__ __forceinline__ float lrelu(float s) { return (s > 0.f) ? s : 0.2f * s; }

// ---------------- CSR build ----------------
__global__ void count_deg_k(const int* __restrict__ ei, int* __restrict__ deg) {
  int e = blockIdx.x * blockDim.x + threadIdx.x;
  if (e >= EP) return;
  int dst = (e < N_EDGES) ? ei[N_EDGES + e] : (e - N_EDGES);
  atomicAdd(&deg[dst], 1);
}

__global__ __launch_bounds__(256) void scan1_k(const int* __restrict__ deg,
                                               int* __restrict__ offs,
                                               int* __restrict__ bsum) {
  __shared__ int buf[256];
  int tid = threadIdx.x, i = blockIdx.x * 256 + tid;
  int v = (i < N_NODES) ? deg[i] : 0;
  buf[tid] = v;
  __syncthreads();
  for (int o = 1; o < 256; o <<= 1) {
    int t = (tid >= o) ? buf[tid - o] : 0;
    __syncthreads();
    buf[tid] += t;
    __syncthreads();
  }
  if (i < N_NODES) offs[i] = buf[tid] - v;   // block-local exclusive
  if (tid == 255) bsum[blockIdx.x] = buf[255];
}

__global__ __launch_bounds__(128) void scan2_k(int* __restrict__ bsum, int nb) {
  __shared__ int buf[128];
  int tid = threadIdx.x;
  int v = (tid < nb) ? bsum[tid] : 0;
  buf[tid] = v;
  __syncthreads();
  for (int o = 1; o < 128; o <<= 1) {
    int t = (tid >= o) ? buf[tid - o] : 0;
    __syncthreads();
    buf[tid] += t;
    __syncthreads();
  }
  if (tid < nb) bsum[tid] = buf[tid] - v;    // exclusive
}

__global__ void scan3_k(int* __restrict__ offs, const int* __restrict__ bsum) {
  int i = blockIdx.x * 256 + threadIdx.x;
  if (i < N_NODES) offs[i] += bsum[blockIdx.x];
  if (i == 0) offs[N_NODES] = EP;
}

__global__ void scatter_k(const int* __restrict__ ei, const int* __restrict__ offs,
                          int* __restrict__ cursor, int* __restrict__ ssrc) {
  int e = blockIdx.x * blockDim.x + threadIdx.x;
  if (e >= EP) return;
  int src, dst;
  if (e < N_EDGES) { src = ei[e]; dst = ei[N_EDGES + e]; }
  else             { src = e - N_EDGES; dst = src; }
  int pos = atomicAdd(&cursor[dst], 1);
  ssrc[offs[dst] + pos] = src;
}

// ---------------- pack [W2 | W3] into Wc[64][320] ----------------
__global__ void pack23_k(const float* __restrict__ W2, const float* __restrict__ W3,
                         float* __restrict__ Wc) {
  int t = blockIdx.x * blockDim.x + threadIdx.x;   // 64*160
  if (t >= 64 * 160) return;
  int k = t / 160, j = t % 160;
  Wc[k * 320 + j]       = W2[t];
  Wc[k * 320 + 160 + j] = W3[t];
}

// ---------------- fp32 tiled GEMM + fused attention-sums epilogue ----------------
// C[M,N] = A[M,K] @ B[K,N]; BM=BN=64, BK=16, 256 threads, 4x4/thread.
// C written in 64-col slices: C[((bn/64)*M + r)*64 + (c-bn)].
// Epilogue: per CH-col unit u (= global_col/CH), as_out[u*M+r] = row . att_s[u].
template <int CH>
__global__ __launch_bounds__(256) void sgemm_fused_k(
    const float* __restrict__ A, const float* __restrict__ B, float* __restrict__ C,
    const float* __restrict__ attAs, const float* __restrict__ attAd,
    const float* __restrict__ attBs, const float* __restrict__ attBd,
    float* __restrict__ as_out, float* __restrict__ ad_out,
    int M, int N, int K) {
  __shared__ float As[16][65];
  __shared__ float Bs[16][65];
  int bm = blockIdx.x * 64, bn = blockIdx.y * 64;
  int tid = threadIdx.x;
  int tr = (tid / 16) * 4;
  int tc = (tid % 16) * 4;
  float acc[4][4] = {};

  int arow = tid >> 2, ac4 = (tid & 3) << 2;
  int brow = tid >> 4, bc4 = (tid & 15) << 2;

  for (int k0 = 0; k0 < K; k0 += 16) {
    float4 a;
    if (bm + arow < M) a = *(const float4*)&A[(size_t)(bm + arow) * K + k0 + ac4];
    else               a = make_float4(0.f, 0.f, 0.f, 0.f);
    As[ac4 + 0][arow] = a.x; As[ac4 + 1][arow] = a.y;
    As[ac4 + 2][arow] = a.z; As[ac4 + 3][arow] = a.w;

    float4 b = *(const float4*)&B[(size_t)(k0 + brow) * N + bn + bc4];
    Bs[brow][bc4 + 0] = b.x; Bs[brow][bc4 + 1] = b.y;
    Bs[brow][bc4 + 2] = b.z; Bs[brow][bc4 + 3] = b.w;
    __syncthreads();

#pragma unroll
    for (int k = 0; k < 16; k++) {
      float av[4], bv[4];
#pragma unroll
      for (int j = 0; j < 4; j++) { av[j] = As[k][tr + j]; bv[j] = Bs[k][tc + j]; }
#pragma unroll
      for (int i = 0; i < 4; i++)
#pragma unroll
        for (int j = 0; j < 4; j++) acc[i][j] += av[i] * bv[j];
    }
    __syncthreads();
  }

  int gs = bn >> 6;
#pragma unroll
  for (int i = 0; i < 4; i++) {
    int r = bm + tr + i;
    if (r < M)
      *(float4*)&C[((size_t)gs * M + r) * 64 + tc] =
          make_float4(acc[i][0], acc[i][1], acc[i][2], acc[i][3]);
  }

  // fused attention sums
  int u  = (bn + tc) / CH;
  int cc = tc % CH;
  const float* avs; const float* avd;
  if (CH == 64)       { avs = attAs + u * 64 + cc;           avd = attAd + u * 64 + cc; }
  else if (u < HEADS) { avs = attAs + u * 32 + cc;           avd = attAd + u * 32 + cc; }
  else                { avs = attBs + (u - HEADS) * 32 + cc; avd = attBd + (u - HEADS) * 32 + cc; }
  float w_s[4], w_d[4];
#pragma unroll
  for (int j = 0; j < 4; j++) { w_s[j] = avs[j]; w_d[j] = avd[j]; }
#pragma unroll
  for (int i = 0; i < 4; i++) {
    float ps = acc[i][0] * w_s[0] + acc[i][1] * w_s[1] + acc[i][2] * w_s[2] + acc[i][3] * w_s[3];
    float pd = acc[i][0] * w_d[0] + acc[i][1] * w_d[1] + acc[i][2] * w_d[2] + acc[i][3] * w_d[3];
#pragma unroll
    for (int o = 1; o < CH / 4; o <<= 1) {
      ps += __shfl_xor(ps, o);
      pd += __shfl_xor(pd, o);
    }
    int r = bm + tr + i;
    if (((tid & ((CH / 4) - 1)) == 0) && r < M) {
      as_out[(size_t)u * M + r] = ps;
      ad_out[(size_t)u * M + r] = pd;
    }
  }
}

// ---------------- layer 1: fused softmax + aggregate, one wave per (unit,node) ----------------
// NOTE: all __shfl broadcasts are hoisted OUT of the divergent tail guard —
// ds_bpermute from an inactive source lane is undefined on CDNA (the R3-R5 bug).
__global__ __launch_bounds__(256) void agg1_k(const int* __restrict__ offs,
                                              const int* __restrict__ ssrc,
                                              const float* __restrict__ a_s,
                                              const float* __restrict__ a_d,
                                              const float* __restrict__ xw,
                                              float* __restrict__ acc_out) {
  int wid = blockIdx.x * 4 + (threadIdx.x >> 6);
  int lane = threadIdx.x & 63;
  if (wid >= N_NODES * HEADS) return;
  int u = wid / N_NODES, n = wid - u * N_NODES;
  int off = offs[n], end = offs[n + 1];
  int deg = end - off;
  float ad = a_d[(size_t)u * N_NODES + n];
  const float* asl = a_s + (size_t)u * N_NODES;
  const float* xb  = xw + (size_t)u * N_NODES * 64;
  int g = lane >> 4, q = lane & 15;
  float ax = 0.f, ay = 0.f, az = 0.f, aw = 0.f;

  if (deg <= 64) {
    int s = 0;
    float e = -1e30f;
    if (lane < deg) { s = ssrc[off + lane]; e = lrelu(asl[s] + ad); }
    float m = e;
#pragma unroll
    for (int o = 32; o > 0; o >>= 1) m = fmaxf(m, __shfl_xor(m, o));
    float p = (lane < deg) ? __expf(e - m) : 0.f;
    float den = p;
#pragma unroll
    for (int o = 32; o > 0; o >>= 1) den += __shfl_xor(den, o);
    float alpha = p * (1.f / (den + 1e-16f));

    for (int base = 0; base < deg; base += 4) {
      int ee = base + g;
      bool ok = ee < deg;
      int es = ok ? ee : 0;             // clamp: keep all lanes + sources active
      float al = __shfl(alpha, es);     // executed by ALL 64 lanes
      int   sv = __shfl(s, es);
      if (ok) {
        float4 v = *(const float4*)&xb[(size_t)sv * 64 + q * 4];
        ax += al * v.x; ay += al * v.y; az += al * v.z; aw += al * v.w;
      }
    }
  } else {
    float m = -1e30f;
    for (int i = off + lane; i < end; i += 64) m = fmaxf(m, lrelu(asl[ssrc[i]] + ad));
#pragma unroll
    for (int o = 32; o > 0; o >>= 1) m = fmaxf(m, __shfl_xor(m, o));
    float den = 0.f;
    for (int i = off + lane; i < end; i += 64) den += __expf(lrelu(asl[ssrc[i]] + ad) - m);
#pragma unroll
    for (int o = 32; o > 0; o >>= 1) den += __shfl_xor(den, o);
    float inv = 1.f / (den + 1e-16f);
    for (int base = off; base < end; base += 4) {
      int e = base + g;
      if (e < end) {
        int sv = ssrc[e];
        float al = __expf(lrelu(asl[sv] + ad) - m) * inv;
        float4 v = *(const float4*)&xb[(size_t)sv * 64 + q * 4];
        ax += al * v.x; ay += al * v.y; az += al * v.z; aw += al * v.w;
      }
    }
  }

#pragma unroll
  for (int o = 16; o < 64; o <<= 1) {
    ax += __shfl_xor(ax, o); ay += __shfl_xor(ay, o);
    az += __shfl_xor(az, o); aw += __shfl_xor(aw, o);
  }
  if (g == 0) {
    float* dst = &acc_out[(size_t)n * 64 + q * 4];
    atomicAdd(dst + 0, ax); atomicAdd(dst + 1, ay);
    atomicAdd(dst + 2, az); atomicAdd(dst + 3, aw);
  }
}

// ---------------- layers 2+3: paired units (2g, 2g+1) share slice g ----------------
__global__ __launch_bounds__(256) void agg23_k(const int* __restrict__ offs,
                                               const int* __restrict__ ssrc,
                                               const float* __restrict__ a_s,
                                               const float* __restrict__ a_d,
                                               const float* __restrict__ xw,
                                               float* __restrict__ acc_out) {
  int wid = blockIdx.x * 4 + (threadIdx.x >> 6);
  int lane = threadIdx.x & 63;
  if (wid >= N_NODES * HEADS) return;
  int gp = wid / N_NODES, n = wid - gp * N_NODES;
  int ulo = 2 * gp, uhi = 2 * gp + 1;
  int off = offs[n], end = offs[n + 1];
  int deg = end - off;
  float adlo = a_d[(size_t)ulo * N_NODES + n];
  float adhi = a_d[(size_t)uhi * N_NODES + n];
  const float* aslo = a_s + (size_t)ulo * N_NODES;
  const float* ashi = a_s + (size_t)uhi * N_NODES;
  const float* xb   = xw + (size_t)gp * N_NODES * 64;
  int g = lane >> 4, q = lane & 15;
  float ax = 0.f, ay = 0.f, az = 0.f, aw = 0.f;

  if (deg <= 64) {
    int s = 0;
    float elo = -1e30f, ehi = -1e30f;
    if (lane < deg) {
      s = ssrc[off + lane];
      elo = lrelu(aslo[s] + adlo);
      ehi = lrelu(ashi[s] + adhi);
    }
    float mlo = elo, mhi = ehi;
#pragma unroll
    for (int o = 32; o > 0; o >>= 1) {
      mlo = fmaxf(mlo, __shfl_xor(mlo, o));
      mhi = fmaxf(mhi, __shfl_xor(mhi, o));
    }
    float plo = (lane < deg) ? __expf(elo - mlo) : 0.f;
    float phi = (lane < deg) ? __expf(ehi - mhi) : 0.f;
    float dlo = plo, dhi = phi;
#pragma unroll
    for (int o = 32; o > 0; o >>= 1) {
      dlo += __shfl_xor(dlo, o);
      dhi += __shfl_xor(dhi, o);
    }
    float allo = plo * (1.f / (dlo + 1e-16f));
    float alhi = phi * (1.f / (dhi + 1e-16f));

    for (int base = 0; base < deg; base += 4) {
      int ee = base + g;
      bool ok = ee < deg;
      int es = ok ? ee : 0;             // clamp: keep all lanes + sources active
      float a1 = __shfl(allo, es);      // executed by ALL 64 lanes
      float a2 = __shfl(alhi, es);
      int   sv = __shfl(s, es);
      if (ok) {
        float al = (q < 8) ? a1 : a2;
        float4 v = *(const float4*)&xb[(size_t)sv * 64 + q * 4];
        ax += al * v.x; ay += al * v.y; az += al * v.z; aw += al * v.w;
      }
    }
  } else {
    float mlo = -1e30f, mhi = -1e30f;
    for (int i = off + lane; i < end; i += 64) {
      int sv = ssrc[i];
      mlo = fmaxf(mlo, lrelu(aslo[sv] + adlo));
      mhi = fmaxf(mhi, lrelu(ashi[sv] + adhi));
    }
#pragma unroll
    for (int o = 32; o > 0; o >>= 1) {
      mlo = fmaxf(mlo, __shfl_xor(mlo, o));
      mhi = fmaxf(mhi, __shfl_xor(mhi, o));
    }
    float dlo = 0.f, dhi = 0.f;
    for (int i = off + lane; i < end; i += 64) {
      int sv = ssrc[i];
      dlo += __expf(lrelu(aslo[sv] + adlo) - mlo);
      dhi += __expf(lrelu(ashi[sv] + adhi) - mhi);
    }
#pragma unroll
    for (int o = 32; o > 0; o >>= 1) {
      dlo += __shfl_xor(dlo, o);
      dhi += __shfl_xor(dhi, o);
    }
    float ilo = 1.f / (dlo + 1e-16f), ihi = 1.f / (dhi + 1e-16f);
    for (int base = off; base < end; base += 4) {
      int e = base + g;
      if (e < end) {
        int sv = ssrc[e];
        float al;
        if (q < 8) al = __expf(lrelu(aslo[sv] + adlo) - mlo) * ilo;
        else       al = __expf(lrelu(ashi[sv] + adhi) - mhi) * ihi;
        float4 v = *(const float4*)&xb[(size_t)sv * 64 + q * 4];
        ax += al * v.x; ay += al * v.y; az += al * v.z; aw += al * v.w;
      }
    }
  }

#pragma unroll
  for (int o = 16; o < 64; o <<= 1) {
    ax += __shfl_xor(ax, o); ay += __shfl_xor(ay, o);
    az += __shfl_xor(az, o); aw += __shfl_xor(aw, o);
  }
  if (g == 0) {
    int u = (q < 8) ? ulo : uhi;
    int col = (u / HEADS) * 32 + (q & 7) * 4;
    float* dst = &acc_out[(size_t)n * 64 + col];
    atomicAdd(dst + 0, ax); atomicAdd(dst + 1, ay);
    atomicAdd(dst + 2, az); atomicAdd(dst + 3, aw);
  }
}

// ---------------- finalize: mean + bias (+relu), in place for layer 1 ----------------
__global__ void red1_k(float* __restrict__ acc, const float* __restrict__ b) {
  int t = blockIdx.x * blockDim.x + threadIdx.x;   // n*16 + q
  if (t >= N_NODES * 16) return;
  int n = t >> 4, q = t & 15;
  float4 v = *(const float4*)&acc[(size_t)n * 64 + q * 4];
  float4 bb = *(const float4*)&b[q * 4];
  float4 o;
  o.x = fmaxf(v.x * 0.2f + bb.x, 0.f);
  o.y = fmaxf(v.y * 0.2f + bb.y, 0.f);
  o.z = fmaxf(v.z * 0.2f + bb.z, 0.f);
  o.w = fmaxf(v.w * 0.2f + bb.w, 0.f);
  *(float4*)&acc[(size_t)n * 64 + q * 4] = o;     // acc becomes h1
}

__global__ void final23_k(const float* __restrict__ acc, const float* __restrict__ b2,
                          const float* __restrict__ b3, float* __restrict__ z_out,
                          float* __restrict__ mu_out, float* __restrict__ lv_out) {
  int t = blockIdx.x * blockDim.x + threadIdx.x;   // n*16 + q
  if (t >= N_NODES * 16) return;
  int n = t >> 4, q = t & 15;
  float4 v = *(const float4*)&acc[(size_t)n * 64 + q * 4];
  if (q < 8) {
    float4 bb = *(const float4*)&b2[q * 4];
    float4 o = make_float4(v.x * 0.2f + bb.x, v.y * 0.2f + bb.y,
                           v.z * 0.2f + bb.z, v.w * 0.2f + bb.w);
    *(float4*)&z_out[(size_t)n * 32 + q * 4]  = o;
    *(float4*)&mu_out[(size_t)n * 32 + q * 4] = o;
  } else {
    float4 bb = *(const float4*)&b3[(q - 8) * 4];
    float4 o = make_float4(v.x * 0.2f + bb.x, v.y * 0.2f + bb.y,
                           v.z * 0.2f + bb.z, v.w * 0.2f + bb.w);
    *(float4*)&lv_out[(size_t)n * 32 + (q - 8) * 4] = o;
  }
}

// ---------------- launch ----------------
extern "C" void kernel_launch(void* const* d_in, const int* in_sizes, int n_in,
                              void* d_out, int out_size, void* d_ws, size_t ws_size,
                              hipStream_t stream) {
  const float* x        = (const float*)d_in[0];
  const int*   ei       = (const int*)d_in[1];
  const float* W1       = (const float*)d_in[2];
  const float* att_src1 = (const float*)d_in[3];
  const float* att_dst1 = (const float*)d_in[4];
  const float* b1       = (const float*)d_in[5];
  const float* W2       = (const float*)d_in[6];
  const float* att_src2 = (const float*)d_in[7];
  const float* att_dst2 = (const float*)d_in[8];
  const float* b2       = (const float*)d_in[9];
  const float* W3       = (const float*)d_in[10];
  const float* att_src3 = (const float*)d_in[11];
  const float* att_dst3 = (const float*)d_in[12];
  const float* b3       = (const float*)d_in[13];
  float* out = (float*)d_out;

  char* w = (char*)d_ws;
  auto alloc = [&](size_t bytes) -> void* {
    void* p = (void*)w;
    w += (bytes + 255) & ~(size_t)255;
    return p;
  };
  int*   deg    = (int*)alloc((size_t)N_NODES * 4);
  int*   offs   = (int*)alloc((size_t)(N_NODES + 1) * 4);
  int*   cursor = (int*)alloc((size_t)N_NODES * 4);
  int*   bsum   = (int*)alloc((size_t)128 * 4);
  int*   ssrc   = (int*)alloc((size_t)EP * 4);
  float* xw     = (float*)alloc((size_t)N_NODES * 320 * 4);   // 25.6 MB, reused L1 then L2|3
  float* a_s    = (float*)alloc((size_t)N_NODES * 10 * 4);
  float* a_d    = (float*)alloc((size_t)N_NODES * 10 * 4);
  float* acc    = (float*)alloc((size_t)N_NODES * 64 * 4);    // 5.12 MB; becomes h1 in place
  float* Wc     = (float*)alloc((size_t)64 * 320 * 4);
  // total ~34.0 MB

  hipMemsetAsync(deg, 0, (size_t)N_NODES * 4, stream);
  hipMemsetAsync(cursor, 0, (size_t)N_NODES * 4, stream);
  hipMemsetAsync(acc, 0, (size_t)N_NODES * 64 * 4, stream);

  int eb = (EP + 255) / 256;
  int nb = (N_NODES + 255) / 256;   // 79
  count_deg_k<<<eb, 256, 0, stream>>>(ei, deg);
  scan1_k<<<nb, 256, 0, stream>>>(deg, offs, bsum);
  scan2_k<<<1, 128, 0, stream>>>(bsum, nb);
  scan3_k<<<nb, 256, 0, stream>>>(offs, bsum);
  scatter_k<<<eb, 256, 0, stream>>>(ei, offs, cursor, ssrc);
  pack23_k<<<40, 256, 0, stream>>>(W2, W3, Wc);

  dim3 gg(313, 5);
  int aggb = (N_NODES * HEADS + 3) / 4;   // 25000 blocks, 4 waves each

  // ---- layer 1 ----
  sgemm_fused_k<64><<<gg, 256, 0, stream>>>(x, W1, xw, att_src1, att_dst1,
                                            nullptr, nullptr, a_s, a_d,
                                            N_NODES, 320, 256);
  agg1_k<<<aggb, 256, 0, stream>>>(offs, ssrc, a_s, a_d, xw, acc);
  red1_k<<<(N_NODES * 16 + 255) / 256, 256, 0, stream>>>(acc, b1);   // acc -> h1

  // ---- layers 2+3 fused ----
  sgemm_fused_k<32><<<gg, 256, 0, stream>>>(acc, Wc, xw, att_src2, att_dst2,
                                            att_src3, att_dst3, a_s, a_d,
                                            N_NODES, 320, 64);
  hipMemsetAsync(acc, 0, (size_t)N_NODES * 64 * 4, stream);          // reuse as acc23
  agg23_k<<<aggb, 256, 0, stream>>>(offs, ssrc, a_s, a_d, xw, acc);
  final23_k<<<(N_NODES * 16 + 255) / 256, 256, 0, stream>>>(acc, b2, b3,
                                                            out, out + (size_t)N_NODES * 32,
                                                            out + (size_t)2 * N_NODES * 32);
}

// Round 7
// 299.882 us; speedup vs baseline: 2.0287x; 1.2069x over previous
//
#include <hip/hip_runtime.h>
#include <math.h>

#define N_NODES 20000
#define N_EDGES 320000
#define EP (N_EDGES + N_NODES)   // with self loops
#define HEADS 5

__device__ __forceinline__ float lrelu(float s) { return (s > 0.f) ? s : 0.2f * s; }

// ---------------- CSR build ----------------
__global__ void count_deg_k(const int* __restrict__ ei, int* __restrict__ deg) {
  int e = blockIdx.x * blockDim.x + threadIdx.x;
  if (e >= EP) return;
  int dst = (e < N_EDGES) ? ei[N_EDGES + e] : (e - N_EDGES);
  atomicAdd(&deg[dst], 1);
}

__global__ __launch_bounds__(256) void scan1_k(const int* __restrict__ deg,
                                               int* __restrict__ offs,
                                               int* __restrict__ bsum) {
  __shared__ int buf[256];
  int tid = threadIdx.x, i = blockIdx.x * 256 + tid;
  int v = (i < N_NODES) ? deg[i] : 0;
  buf[tid] = v;
  __syncthreads();
  for (int o = 1; o < 256; o <<= 1) {
    int t = (tid >= o) ? buf[tid - o] : 0;
    __syncthreads();
    buf[tid] += t;
    __syncthreads();
  }
  if (i < N_NODES) offs[i] = buf[tid] - v;   // block-local exclusive
  if (tid == 255) bsum[blockIdx.x] = buf[255];
}

__global__ __launch_bounds__(128) void scan2_k(int* __restrict__ bsum, int nb) {
  __shared__ int buf[128];
  int tid = threadIdx.x;
  int v = (tid < nb) ? bsum[tid] : 0;
  buf[tid] = v;
  __syncthreads();
  for (int o = 1; o < 128; o <<= 1) {
    int t = (tid >= o) ? buf[tid - o] : 0;
    __syncthreads();
    buf[tid] += t;
    __syncthreads();
  }
  if (tid < nb) bsum[tid] = buf[tid] - v;    // exclusive
}

__global__ void scan3_k(int* __restrict__ offs, const int* __restrict__ bsum) {
  int i = blockIdx.x * 256 + threadIdx.x;
  if (i < N_NODES) offs[i] += bsum[blockIdx.x];
  if (i == 0) offs[N_NODES] = EP;
}

__global__ void scatter_k(const int* __restrict__ ei, const int* __restrict__ offs,
                          int* __restrict__ cursor, int* __restrict__ ssrc) {
  int e = blockIdx.x * blockDim.x + threadIdx.x;
  if (e >= EP) return;
  int src, dst;
  if (e < N_EDGES) { src = ei[e]; dst = ei[N_EDGES + e]; }
  else             { src = e - N_EDGES; dst = src; }
  int pos = atomicAdd(&cursor[dst], 1);
  ssrc[offs[dst] + pos] = src;
}

// ---------------- pack [W2 | W3] into Wc[64][320] ----------------
__global__ void pack23_k(const float* __restrict__ W2, const float* __restrict__ W3,
                         float* __restrict__ Wc) {
  int t = blockIdx.x * blockDim.x + threadIdx.x;   // 64*160
  if (t >= 64 * 160) return;
  int k = t / 160, j = t % 160;
  Wc[k * 320 + j]       = W2[t];
  Wc[k * 320 + 160 + j] = W3[t];
}

// ---------------- fp32 tiled GEMM + fused attention-sums epilogue ----------------
// C[M,N] = A[M,K] @ B[K,N]; BM=BN=64, BK=16, 256 threads, 4x4/thread.
// C written in 64-col slices: C[((bn/64)*M + r)*64 + (c-bn)].
// Epilogue: per CH-col unit u (= global_col/CH), as_out[u*M+r] = row . att_s[u].
template <int CH>
__global__ __launch_bounds__(256) void sgemm_fused_k(
    const float* __restrict__ A, const float* __restrict__ B, float* __restrict__ C,
    const float* __restrict__ attAs, const float* __restrict__ attAd,
    const float* __restrict__ attBs, const float* __restrict__ attBd,
    float* __restrict__ as_out, float* __restrict__ ad_out,
    int M, int N, int K) {
  __shared__ float As[16][65];
  __shared__ float Bs[16][65];
  int bm = blockIdx.x * 64, bn = blockIdx.y * 64;
  int tid = threadIdx.x;
  int tr = (tid / 16) * 4;
  int tc = (tid % 16) * 4;
  float acc[4][4] = {};

  int arow = tid >> 2, ac4 = (tid & 3) << 2;
  int brow = tid >> 4, bc4 = (tid & 15) << 2;

  for (int k0 = 0; k0 < K; k0 += 16) {
    float4 a;
    if (bm + arow < M) a = *(const float4*)&A[(size_t)(bm + arow) * K + k0 + ac4];
    else               a = make_float4(0.f, 0.f, 0.f, 0.f);
    As[ac4 + 0][arow] = a.x; As[ac4 + 1][arow] = a.y;
    As[ac4 + 2][arow] = a.z; As[ac4 + 3][arow] = a.w;

    float4 b = *(const float4*)&B[(size_t)(k0 + brow) * N + bn + bc4];
    Bs[brow][bc4 + 0] = b.x; Bs[brow][bc4 + 1] = b.y;
    Bs[brow][bc4 + 2] = b.z; Bs[brow][bc4 + 3] = b.w;
    __syncthreads();

#pragma unroll
    for (int k = 0; k < 16; k++) {
      float av[4], bv[4];
#pragma unroll
      for (int j = 0; j < 4; j++) { av[j] = As[k][tr + j]; bv[j] = Bs[k][tc + j]; }
#pragma unroll
      for (int i = 0; i < 4; i++)
#pragma unroll
        for (int j = 0; j < 4; j++) acc[i][j] += av[i] * bv[j];
    }
    __syncthreads();
  }

  int gs = bn >> 6;
#pragma unroll
  for (int i = 0; i < 4; i++) {
    int r = bm + tr + i;
    if (r < M)
      *(float4*)&C[((size_t)gs * M + r) * 64 + tc] =
          make_float4(acc[i][0], acc[i][1], acc[i][2], acc[i][3]);
  }

  // fused attention sums
  int u  = (bn + tc) / CH;
  int cc = tc % CH;
  const float* avs; const float* avd;
  if (CH == 64)       { avs = attAs + u * 64 + cc;           avd = attAd + u * 64 + cc; }
  else if (u < HEADS) { avs = attAs + u * 32 + cc;           avd = attAd + u * 32 + cc; }
  else                { avs = attBs + (u - HEADS) * 32 + cc; avd = attBd + (u - HEADS) * 32 + cc; }
  float w_s[4], w_d[4];
#pragma unroll
  for (int j = 0; j < 4; j++) { w_s[j] = avs[j]; w_d[j] = avd[j]; }
#pragma unroll
  for (int i = 0; i < 4; i++) {
    float ps = acc[i][0] * w_s[0] + acc[i][1] * w_s[1] + acc[i][2] * w_s[2] + acc[i][3] * w_s[3];
    float pd = acc[i][0] * w_d[0] + acc[i][1] * w_d[1] + acc[i][2] * w_d[2] + acc[i][3] * w_d[3];
#pragma unroll
    for (int o = 1; o < CH / 4; o <<= 1) {
      ps += __shfl_xor(ps, o);
      pd += __shfl_xor(pd, o);
    }
    int r = bm + tr + i;
    if (((tid & ((CH / 4) - 1)) == 0) && r < M) {
      as_out[(size_t)u * M + r] = ps;
      ad_out[(size_t)u * M + r] = pd;
    }
  }
}

// ---------------- layer 1: block per node, 5 waves (wave = head), LDS reduce ----------------
// __shfl broadcasts stay OUTSIDE divergent guards (ds_bpermute from inactive lane
// is undefined on CDNA — was the R3-R5 bug).
__global__ __launch_bounds__(320) void agg1_k(const int* __restrict__ offs,
                                              const int* __restrict__ ssrc,
                                              const float* __restrict__ a_s,
                                              const float* __restrict__ a_d,
                                              const float* __restrict__ xw,
                                              const float* __restrict__ b1,
                                              float* __restrict__ h1) {
  int n = blockIdx.x;
  int u = threadIdx.x >> 6;          // wave = head/unit
  int lane = threadIdx.x & 63;
  int off = offs[n], end = offs[n + 1];
  int deg = end - off;
  float ad = a_d[(size_t)u * N_NODES + n];
  const float* asl = a_s + (size_t)u * N_NODES;
  const float* xb  = xw + (size_t)u * N_NODES * 64;
  int g = lane >> 4, q = lane & 15;
  float ax = 0.f, ay = 0.f, az = 0.f, aw = 0.f;

  if (deg <= 64) {
    int s = 0;
    float e = -1e30f;
    if (lane < deg) { s = ssrc[off + lane]; e = lrelu(asl[s] + ad); }
    float m = e;
#pragma unroll
    for (int o = 32; o > 0; o >>= 1) m = fmaxf(m, __shfl_xor(m, o));
    float p = (lane < deg) ? __expf(e - m) : 0.f;
    float den = p;
#pragma unroll
    for (int o = 32; o > 0; o >>= 1) den += __shfl_xor(den, o);
    float alpha = p * (1.f / (den + 1e-16f));

    for (int base = 0; base < deg; base += 4) {
      int ee = base + g;
      bool ok = ee < deg;
      int es = ok ? ee : 0;             // clamp: all lanes + sources active
      float al = __shfl(alpha, es);
      int   sv = __shfl(s, es);
      if (ok) {
        float4 v = *(const float4*)&xb[(size_t)sv * 64 + q * 4];
        ax += al * v.x; ay += al * v.y; az += al * v.z; aw += al * v.w;
      }
    }
  } else {
    float m = -1e30f;
    for (int i = off + lane; i < end; i += 64) m = fmaxf(m, lrelu(asl[ssrc[i]] + ad));
#pragma unroll
    for (int o = 32; o > 0; o >>= 1) m = fmaxf(m, __shfl_xor(m, o));
    float den = 0.f;
    for (int i = off + lane; i < end; i += 64) den += __expf(lrelu(asl[ssrc[i]] + ad) - m);
#pragma unroll
    for (int o = 32; o > 0; o >>= 1) den += __shfl_xor(den, o);
    float inv = 1.f / (den + 1e-16f);
    for (int base = off; base < end; base += 4) {
      int e = base + g;
      if (e < end) {
        int sv = ssrc[e];
        float al = __expf(lrelu(asl[sv] + ad) - m) * inv;
        float4 v = *(const float4*)&xb[(size_t)sv * 64 + q * 4];
        ax += al * v.x; ay += al * v.y; az += al * v.z; aw += al * v.w;
      }
    }
  }

#pragma unroll
  for (int o = 16; o < 64; o <<= 1) {
    ax += __shfl_xor(ax, o); ay += __shfl_xor(ay, o);
    az += __shfl_xor(az, o); aw += __shfl_xor(aw, o);
  }

  __shared__ float sacc[HEADS][64];
  if (g == 0) *(float4*)&sacc[u][q * 4] = make_float4(ax, ay, az, aw);
  __syncthreads();
  if (threadIdx.x < 64) {
    int t = threadIdx.x;
    float v = sacc[0][t] + sacc[1][t] + sacc[2][t] + sacc[3][t] + sacc[4][t];
    v = v * 0.2f + b1[t];
    h1[(size_t)n * 64 + t] = fmaxf(v, 0.f);
  }
}

// ---------------- layers 2+3: block per node, 5 waves (wave = pair 2g,2g+1) ----------------
// slice g: cols 0-31 = unit 2g, cols 32-63 = unit 2g+1. Units 0-4 -> layer2, 5-9 -> layer3.
__global__ __launch_bounds__(320) void agg23_k(const int* __restrict__ offs,
                                               const int* __restrict__ ssrc,
                                               const float* __restrict__ a_s,
                                               const float* __restrict__ a_d,
                                               const float* __restrict__ xw,
                                               const float* __restrict__ b2,
                                               const float* __restrict__ b3,
                                               float* __restrict__ z_out,
                                               float* __restrict__ mu_out,
                                               float* __restrict__ lv_out) {
  int n = blockIdx.x;
  int gp = threadIdx.x >> 6;         // wave = pair index
  int lane = threadIdx.x & 63;
  int ulo = 2 * gp, uhi = 2 * gp + 1;
  int off = offs[n], end = offs[n + 1];
  int deg = end - off;
  float adlo = a_d[(size_t)ulo * N_NODES + n];
  float adhi = a_d[(size_t)uhi * N_NODES + n];
  const float* aslo = a_s + (size_t)ulo * N_NODES;
  const float* ashi = a_s + (size_t)uhi * N_NODES;
  const float* xb   = xw + (size_t)gp * N_NODES * 64;
  int g = lane >> 4, q = lane & 15;
  float ax = 0.f, ay = 0.f, az = 0.f, aw = 0.f;

  if (deg <= 64) {
    int s = 0;
    float elo = -1e30f, ehi = -1e30f;
    if (lane < deg) {
      s = ssrc[off + lane];
      elo = lrelu(aslo[s] + adlo);
      ehi = lrelu(ashi[s] + adhi);
    }
    float mlo = elo, mhi = ehi;
#pragma unroll
    for (int o = 32; o > 0; o >>= 1) {
      mlo = fmaxf(mlo, __shfl_xor(mlo, o));
      mhi = fmaxf(mhi, __shfl_xor(mhi, o));
    }
    float plo = (lane < deg) ? __expf(elo - mlo) : 0.f;
    float phi = (lane < deg) ? __expf(ehi - mhi) : 0.f;
    float dlo = plo, dhi = phi;
#pragma unroll
    for (int o = 32; o > 0; o >>= 1) {
      dlo += __shfl_xor(dlo, o);
      dhi += __shfl_xor(dhi, o);
    }
    float allo = plo * (1.f / (dlo + 1e-16f));
    float alhi = phi * (1.f / (dhi + 1e-16f));

    for (int base = 0; base < deg; base += 4) {
      int ee = base + g;
      bool ok = ee < deg;
      int es = ok ? ee : 0;
      float a1 = __shfl(allo, es);
      float a2 = __shfl(alhi, es);
      int   sv = __shfl(s, es);
      if (ok) {
        float al = (q < 8) ? a1 : a2;
        float4 v = *(const float4*)&xb[(size_t)sv * 64 + q * 4];
        ax += al * v.x; ay += al * v.y; az += al * v.z; aw += al * v.w;
      }
    }
  } else {
    float mlo = -1e30f, mhi = -1e30f;
    for (int i = off + lane; i < end; i += 64) {
      int sv = ssrc[i];
      mlo = fmaxf(mlo, lrelu(aslo[sv] + adlo));
      mhi = fmaxf(mhi, lrelu(ashi[sv] + adhi));
    }
#pragma unroll
    for (int o = 32; o > 0; o >>= 1) {
      mlo = fmaxf(mlo, __shfl_xor(mlo, o));
      mhi = fmaxf(mhi, __shfl_xor(mhi, o));
    }
    float dlo = 0.f, dhi = 0.f;
    for (int i = off + lane; i < end; i += 64) {
      int sv = ssrc[i];
      dlo += __expf(lrelu(aslo[sv] + adlo) - mlo);
      dhi += __expf(lrelu(ashi[sv] + adhi) - mhi);
    }
#pragma unroll
    for (int o = 32; o > 0; o >>= 1) {
      dlo += __shfl_xor(dlo, o);
      dhi += __shfl_xor(dhi, o);
    }
    float ilo = 1.f / (dlo + 1e-16f), ihi = 1.f / (dhi + 1e-16f);
    for (int base = off; base < end; base += 4) {
      int e = base + g;
      if (e < end) {
        int sv = ssrc[e];
        float al;
        if (q < 8) al = __expf(lrelu(aslo[sv] + adlo) - mlo) * ilo;
        else       al = __expf(lrelu(ashi[sv] + adhi) - mhi) * ihi;
        float4 v = *(const float4*)&xb[(size_t)sv * 64 + q * 4];
        ax += al * v.x; ay += al * v.y; az += al * v.z; aw += al * v.w;
      }
    }
  }

#pragma unroll
  for (int o = 16; o < 64; o <<= 1) {
    ax += __shfl_xor(ax, o); ay += __shfl_xor(ay, o);
    az += __shfl_xor(az, o); aw += __shfl_xor(aw, o);
  }

  __shared__ float sacc[HEADS][2][32];
  if (g == 0)
    *(float4*)&sacc[gp][q >> 3][(q & 7) * 4] = make_float4(ax, ay, az, aw);
  __syncthreads();
  if (threadIdx.x < 64) {
    int t = threadIdx.x;
    if (t < 32) {
      // layer 2 = units 0..4 = (pair,half): (0,0),(0,1),(1,0),(1,1),(2,0)
      float v = sacc[0][0][t] + sacc[0][1][t] + sacc[1][0][t] + sacc[1][1][t] + sacc[2][0][t];
      v = v * 0.2f + b2[t];
      z_out[(size_t)n * 32 + t]  = v;
      mu_out[(size_t)n * 32 + t] = v;
    } else {
      int c = t - 32;
      // layer 3 = units 5..9 = (2,1),(3,0),(3,1),(4,0),(4,1)
      float v = sacc[2][1][c] + sacc[3][0][c] + sacc[3][1][c] + sacc[4][0][c] + sacc[4][1][c];
      v = v * 0.2f + b3[c];
      lv_out[(size_t)n * 32 + c] = v;
    }
  }
}

// ---------------- launch ----------------
extern "C" void kernel_launch(void* const* d_in, const int* in_sizes, int n_in,
                              void* d_out, int out_size, void* d_ws, size_t ws_size,
                              hipStream_t stream) {
  const float* x        = (const float*)d_in[0];
  const int*   ei       = (const int*)d_in[1];
  const float* W1       = (const float*)d_in[2];
  const float* att_src1 = (const float*)d_in[3];
  const float* att_dst1 = (const float*)d_in[4];
  const float* b1       = (const float*)d_in[5];
  const float* W2       = (const float*)d_in[6];
  const float* att_src2 = (const float*)d_in[7];
  const float* att_dst2 = (const float*)d_in[8];
  const float* b2       = (const float*)d_in[9];
  const float* W3       = (const float*)d_in[10];
  const float* att_src3 = (const float*)d_in[11];
  const float* att_dst3 = (const float*)d_in[12];
  const float* b3       = (const float*)d_in[13];
  float* out = (float*)d_out;

  char* w = (char*)d_ws;
  auto alloc = [&](size_t bytes) -> void* {
    void* p = (void*)w;
    w += (bytes + 255) & ~(size_t)255;
    return p;
  };
  int*   deg    = (int*)alloc((size_t)N_NODES * 4);
  int*   offs   = (int*)alloc((size_t)(N_NODES + 1) * 4);
  int*   cursor = (int*)alloc((size_t)N_NODES * 4);
  int*   bsum   = (int*)alloc((size_t)128 * 4);
  int*   ssrc   = (int*)alloc((size_t)EP * 4);
  float* xw     = (float*)alloc((size_t)N_NODES * 320 * 4);   // 25.6 MB, reused L1 then L2|3
  float* a_s    = (float*)alloc((size_t)N_NODES * 10 * 4);
  float* a_d    = (float*)alloc((size_t)N_NODES * 10 * 4);
  float* h1     = (float*)alloc((size_t)N_NODES * 64 * 4);    // 5.12 MB
  float* Wc     = (float*)alloc((size_t)64 * 320 * 4);
  // total ~33.5 MB

  hipMemsetAsync(deg, 0, (size_t)N_NODES * 4, stream);
  hipMemsetAsync(cursor, 0, (size_t)N_NODES * 4, stream);

  int eb = (EP + 255) / 256;
  int nb = (N_NODES + 255) / 256;   // 79
  count_deg_k<<<eb, 256, 0, stream>>>(ei, deg);
  scan1_k<<<nb, 256, 0, stream>>>(deg, offs, bsum);
  scan2_k<<<1, 128, 0, stream>>>(bsum, nb);
  scan3_k<<<nb, 256, 0, stream>>>(offs, bsum);
  scatter_k<<<eb, 256, 0, stream>>>(ei, offs, cursor, ssrc);
  pack23_k<<<40, 256, 0, stream>>>(W2, W3, Wc);

  dim3 gg(313, 5);

  // ---- layer 1 ----
  sgemm_fused_k<64><<<gg, 256, 0, stream>>>(x, W1, xw, att_src1, att_dst1,
                                            nullptr, nullptr, a_s, a_d,
                                            N_NODES, 320, 256);
  agg1_k<<<N_NODES, 320, 0, stream>>>(offs, ssrc, a_s, a_d, xw, b1, h1);

  // ---- layers 2+3 fused ----
  sgemm_fused_k<32><<<gg, 256, 0, stream>>>(h1, Wc, xw, att_src2, att_dst2,
                                            att_src3, att_dst3, a_s, a_d,
                                            N_NODES, 320, 64);
  agg23_k<<<N_NODES, 320, 0, stream>>>(offs, ssrc, a_s, a_d, xw, b2, b3,
                                       out, out + (size_t)N_NODES * 32,
                                       out + (size_t)2 * N_NODES * 32);
}